// Round 1
// baseline (528.588 us; speedup 1.0000x reference)
//
#include <hip/hip_runtime.h>

typedef unsigned short u16;
typedef unsigned char u8;
typedef __bf16 bf16x8 __attribute__((ext_vector_type(8)));
typedef float f32x4 __attribute__((ext_vector_type(4)));
typedef int i32x4 __attribute__((ext_vector_type(4)));
typedef int i32x8 __attribute__((ext_vector_type(8)));

__device__ __forceinline__ u16 f2bf(float f) {
    unsigned u = __float_as_uint(f);
    unsigned r = (u + 0x7fffu + ((u >> 16) & 1u)) >> 16;
    return (u16)r;
}
__device__ __forceinline__ float bf2f(u16 h) {
    return __uint_as_float(((unsigned)h) << 16);
}
// pack two floats to bf16x2 (lo in low half), round-half-up, single v_perm
__device__ __forceinline__ unsigned pack_bf2(float lo, float hi) {
    unsigned a = __float_as_uint(hi) + 0x8000u;
    unsigned b = __float_as_uint(lo) + 0x8000u;
    return __builtin_amdgcn_perm(a, b, 0x07060302u);
}
// pack 4 floats to 4 fp8 e4m3 bytes
__device__ __forceinline__ unsigned pack_fp8x4(float a, float b, float c, float d) {
    unsigned w = __builtin_amdgcn_cvt_pk_fp8_f32(a, b, 0, false);
    w = __builtin_amdgcn_cvt_pk_fp8_f32(c, d, w, true);
    return w;
}
__device__ __forceinline__ void async_copy16(const void* g, void* l) {
    __builtin_amdgcn_global_load_lds((__attribute__((address_space(1))) void*)(void*)g,
                                     (__attribute__((address_space(3))) void*)l, 16, 0, 0);
}

#define FP8_SCALE 64.0f          // pre-scale before e4m3 quant (avoids subnormals)
#define FP8_UNSCALE (1.0f / 4096.0f)  // (1/64)^2 applied at GEMM epilogue

// ---------------- prep kernels ----------------

__global__ void inv4_k(const int* __restrict__ q, const int* __restrict__ k,
                       const int* __restrict__ v, const int* __restrict__ o,
                       int* __restrict__ invq, int* __restrict__ invk,
                       int* __restrict__ invv, int* __restrict__ invo) {
    int i = blockIdx.x * 256 + threadIdx.x;   // grid 64 -> 16384 = 4*4096
    int a = i >> 12, j = i & 4095;
    const int* p = a == 0 ? q : a == 1 ? k : a == 2 ? v : o;
    int* inv = a == 0 ? invq : a == 1 ? invk : a == 2 ? invv : invo;
    inv[p[j]] = j;
}

// Weight permutations. Q,K rows -> fp8 (x64, XOR-swizzled 16B blocks); V,O rows -> bf16.
// Q,K additionally get a head-dim COLUMN permutation P (applied by selecting permuted
// weight rows) so RoPE pairs (d, d+64) land in adjacent j-fragments of one lane in the
// MFMA C-layout.  QK^T is invariant: Q and K share the same P.
//   P[hd] = (hd&15) | ((b&1)<<6) | ((b&2)<<3) | ((hd&64)>>1),  b = hd>>4
__global__ __launch_bounds__(256) void permw4_k(
    const float* __restrict__ Wq, const float* __restrict__ Wk,
    const float* __restrict__ Wv, const float* __restrict__ Wo,
    const int* __restrict__ qor, const int* __restrict__ kor,
    const int* __restrict__ vor, const int* __restrict__ oor,
    const int* __restrict__ invq, const int* __restrict__ invk,
    const int* __restrict__ invv, const int* __restrict__ invo,
    u8* __restrict__ Wqkf8, u16* __restrict__ Wvp, u16* __restrict__ Wop) {
    __shared__ float rowbuf[4096];
    int j = blockIdx.x;
    const float* W; const int* rp; const int* inv; int row; int f8;
    u8* out8 = nullptr; u16* out16 = nullptr;
    if (j < 4096)      { W = Wq; rp = qor; inv = invq; row = j;        out8 = Wqkf8 + (size_t)j * 4096; f8 = 1; }
    else if (j < 5120) { W = Wk; rp = kor; inv = invk; row = j - 4096; out8 = Wqkf8 + (size_t)j * 4096; f8 = 1; }
    else if (j < 6144) { W = Wv; rp = vor; inv = invv; row = j - 5120; out16 = Wvp + (size_t)(j - 5120) * 4096; f8 = 0; }
    else               { W = Wo; rp = oor; inv = invo; row = j - 6144; out16 = Wop + (size_t)(j - 6144) * 4096; f8 = 0; }
    if (f8) {   // head-dim column permutation for Q,K (RoPE pairing)
        int hd = row & 127, b = hd >> 4;
        row = (row & ~127) | ((hd & 15) | ((b & 1) << 6) | ((b & 2) << 3) | ((hd & 64) >> 1));
    }
    const float4* wr4 = (const float4*)(W + (size_t)rp[row] * 4096);
#pragma unroll
    for (int t = 0; t < 4; t++)
        ((float4*)rowbuf)[threadIdx.x + t * 256] = wr4[threadIdx.x + t * 256];
    __syncthreads();
    if (f8) {
        int t = threadIdx.x;                       // one 16B block per thread
        const int4* inv4p = (const int4*)inv;
        float v[16];
#pragma unroll
        for (int u = 0; u < 4; u++) {
            int4 ix = inv4p[t * 4 + u];
            v[4 * u + 0] = rowbuf[ix.x] * FP8_SCALE;
            v[4 * u + 1] = rowbuf[ix.y] * FP8_SCALE;
            v[4 * u + 2] = rowbuf[ix.z] * FP8_SCALE;
            v[4 * u + 3] = rowbuf[ix.w] * FP8_SCALE;
        }
        uint4 wv;
        wv.x = pack_fp8x4(v[0], v[1], v[2], v[3]);
        wv.y = pack_fp8x4(v[4], v[5], v[6], v[7]);
        wv.z = pack_fp8x4(v[8], v[9], v[10], v[11]);
        wv.w = pack_fp8x4(v[12], v[13], v[14], v[15]);
        int tb = (t & ~7) | ((t & 7) ^ (j & 7));   // XOR swizzle within 128B segment
        ((uint4*)out8)[tb] = wv;
    } else {
        unsigned* o32 = (unsigned*)out16;
        const int2* inv2 = (const int2*)inv;
#pragma unroll
        for (int t = 0; t < 8; t++) {
            int c = threadIdx.x + t * 256;
            int2 ij = inv2[c];
            o32[c] = pack_bf2(rowbuf[ij.x], rowbuf[ij.y]);
        }
    }
}

// hidden -> Xb (bf16) + Xf8 (fp8 x64, swizzled). One block per row of 4096.
__global__ __launch_bounds__(256) void cvt_k(const float* __restrict__ x,
                                             u16* __restrict__ Xb,
                                             u8* __restrict__ Xf8) {
    int row = blockIdx.x;
    int t = threadIdx.x;                           // 16 consecutive floats per thread
    const float4* src = (const float4*)(x + (size_t)row * 4096);
    float v[16];
#pragma unroll
    for (int u = 0; u < 4; u++) {
        float4 a = src[t * 4 + u];
        v[4 * u + 0] = a.x; v[4 * u + 1] = a.y; v[4 * u + 2] = a.z; v[4 * u + 3] = a.w;
    }
    uint4 b0, b1;
    b0.x = pack_bf2(v[0], v[1]);  b0.y = pack_bf2(v[2], v[3]);
    b0.z = pack_bf2(v[4], v[5]);  b0.w = pack_bf2(v[6], v[7]);
    b1.x = pack_bf2(v[8], v[9]);  b1.y = pack_bf2(v[10], v[11]);
    b1.z = pack_bf2(v[12], v[13]); b1.w = pack_bf2(v[14], v[15]);
    uint4* ob = (uint4*)(Xb + (size_t)row * 4096);
    ob[t * 2] = b0;
    ob[t * 2 + 1] = b1;
    uint4 w8;
    w8.x = pack_fp8x4(v[0] * FP8_SCALE, v[1] * FP8_SCALE, v[2] * FP8_SCALE, v[3] * FP8_SCALE);
    w8.y = pack_fp8x4(v[4] * FP8_SCALE, v[5] * FP8_SCALE, v[6] * FP8_SCALE, v[7] * FP8_SCALE);
    w8.z = pack_fp8x4(v[8] * FP8_SCALE, v[9] * FP8_SCALE, v[10] * FP8_SCALE, v[11] * FP8_SCALE);
    w8.w = pack_fp8x4(v[12] * FP8_SCALE, v[13] * FP8_SCALE, v[14] * FP8_SCALE, v[15] * FP8_SCALE);
    int tb = (t & ~7) | ((t & 7) ^ (row & 7));
    ((uint4*)(Xf8 + (size_t)row * 4096))[tb] = w8;
}

// V transpose (sums split-K fp32 partials, kappa-permuted cols). 512 blocks: 32 x 16.
__global__ __launch_bounds__(256) void vtr_k(const float* __restrict__ Vpart,
                                             u16* __restrict__ Vt) {
    __shared__ u16 t[64][65];
    int bx = blockIdx.x;
    int s0 = (bx & 31) * 64, c0 = (bx >> 5) * 64;
    int x = threadIdx.x & 63, y4 = threadIdx.x >> 6;
    const float* Vp0 = Vpart;
    const float* Vp1 = Vpart + (size_t)2048 * 1024;
    for (int i = 0; i < 16; i++) {
        int r = y4 * 16 + i;
        size_t idx = (size_t)(s0 + r) * 1024 + c0 + x;
        t[r][x] = f2bf(Vp0[idx] + Vp1[idx]);
    }
    __syncthreads();
    for (int i = 0; i < 16; i++) {
        int r = y4 * 16 + i;
        int xk = 4 * (x & 15) + (x >> 4);  // kappa permutation within 64-key tile
        Vt[(size_t)(c0 + r) * 2048 + s0 + xk] = t[x][r];
    }
}

// ---------------- merged QKV GEMM (balanced) ----------------
// blocks x<40: Q,K via MX-fp8 (128x128 tile, BK=128, 32 iters) + fused RoPE epilogue
// blocks x in [40,56): V via bf16, 2-way split-K, BK=64 -> 32 iters, fp32 partials.

__global__ __launch_bounds__(256) void gemm_qkv_k(const u8* __restrict__ Xf8,
                                                  const u16* __restrict__ Xb,
                                                  const u8* __restrict__ Wqk,
                                                  const u16* __restrict__ Wv,
                                                  u16* __restrict__ QKV,
                                                  float* __restrict__ Vpart,
                                                  const float* __restrict__ cosv,
                                                  const float* __restrict__ sinv) {
    __shared__ u8 lds[32768];
    const int tid = threadIdx.x;
    const int w = tid >> 6, lane = tid & 63;
    const int quad = lane >> 4, l16 = lane & 15;
    const int bm0 = blockIdx.y * 128;
    const int wm = (w >> 1) * 64, wn = (w & 1) * 64;
    if (blockIdx.x < 40) {
        const int bn0 = blockIdx.x * 128;
        u8* ldsA = lds;
        u8* ldsB = lds + 16384;
        const u8* Ag = Xf8 + (size_t)(bm0 + w * 32 + (lane >> 3)) * 4096 + (lane & 7) * 16;
        const u8* Bg = Wqk + (size_t)(bn0 + w * 32 + (lane >> 3)) * 4096 + (lane & 7) * 16;
        u8* la = ldsA + w * 32 * 128;
        u8* lb = ldsB + w * 32 * 128;
        const int swz = l16 & 7;   // (fragment row)&7 for XOR de-swizzle
        f32x4 acc[4][4] = {};
        for (int k0 = 0; k0 < 4096; k0 += 128) {
#pragma unroll
            for (int t = 0; t < 4; t++) async_copy16(Ag + (size_t)t * 8 * 4096 + k0, la + t * 1024);
#pragma unroll
            for (int t = 0; t < 4; t++) async_copy16(Bg + (size_t)t * 8 * 4096 + k0, lb + t * 1024);
            __syncthreads();
            i32x8 af[4], bf[4];
#pragma unroll
            for (int i = 0; i < 4; i++) {
                int r = wm + i * 16 + l16;
                union { i32x8 v8; i32x4 v4[2]; } u;
                u.v4[0] = *(const i32x4*)&ldsA[r * 128 + ((quad * 2) ^ swz) * 16];
                u.v4[1] = *(const i32x4*)&ldsA[r * 128 + ((quad * 2 + 1) ^ swz) * 16];
                af[i] = u.v8;
            }
#pragma unroll
            for (int j = 0; j < 4; j++) {
                int r = wn + j * 16 + l16;
                union { i32x8 v8; i32x4 v4[2]; } u;
                u.v4[0] = *(const i32x4*)&ldsB[r * 128 + ((quad * 2) ^ swz) * 16];
                u.v4[1] = *(const i32x4*)&ldsB[r * 128 + ((quad * 2 + 1) ^ swz) * 16];
                bf[j] = u.v8;
            }
#pragma unroll
            for (int i = 0; i < 4; i++)
#pragma unroll
                for (int j = 0; j < 4; j++)
                    acc[i][j] = __builtin_amdgcn_mfma_scale_f32_16x16x128_f8f6f4(
                        af[i], bf[j], acc[i][j], 0, 0,
                        0, 0x7F7F7F7F, 0, 0x7F7F7F7F);
            __syncthreads();
        }
        // fused RoPE epilogue: with the P column permutation, lane's cols hold
        //   j even -> head-dim d1, j odd -> head-dim d1+64 (same lane, same rows).
        //   cos[s,d1+64]==cos[s,d1], sin likewise.
        const float qsc = (bn0 < 4096) ? 0.08838834764831845f : 1.0f;  // 1/sqrt(128) for Q
        const int hb = (wn ? 32 : 0) + l16;
#pragma unroll
        for (int i = 0; i < 4; i++) {
            const int row = bm0 + wm + i * 16 + quad * 4;
#pragma unroll
            for (int jp = 0; jp < 2; jp++) {       // pair groups (j=0,1) and (j=2,3)
                const int d1 = hb + jp * 16;
                const int ce = bn0 + wn + jp * 32 + l16;
#pragma unroll
                for (int r = 0; r < 4; r++) {
                    const int s = row + r;
                    const float c  = cosv[s * 128 + d1];
                    const float sn = sinv[s * 128 + d1];
                    const float x1 = acc[i][jp * 2][r]     * FP8_UNSCALE;
                    const float x2 = acc[i][jp * 2 + 1][r] * FP8_UNSCALE;
                    QKV[(size_t)s * 6144 + ce]      = f2bf((x1 * c - x2 * sn) * qsc);
                    QKV[(size_t)s * 6144 + ce + 16] = f2bf((x2 * c + x1 * sn) * qsc);
                }
            }
        }
    } else {
        const int vx = blockIdx.x - 40;        // 16 slots: 8 n-tiles x 2 k-slices
        const int bn0 = (vx & 7) * 128;
        const int kslice = vx >> 3;
        const int kb = kslice * 2048;
        u16* lds_a0 = (u16*)lds;               // [128*32] each
        u16* lds_a1 = (u16*)(lds + 8192);
        u16* lds_b0 = (u16*)(lds + 16384);
        u16* lds_b1 = (u16*)(lds + 24576);
        const int r0 = w * 16 + (lane >> 2);
        const int c0 = (lane & 3) * 8;
        const u16* Ag = Xb + (size_t)(bm0 + r0) * 4096 + kb + c0;
        const u16* Bg = Wv + (size_t)(bn0 + r0) * 4096 + kb + c0;
        f32x4 acc[4][4] = {};
        for (int k0 = 0; k0 < 2048; k0 += 64) {
            async_copy16(Ag + k0,                         lds_a0 + w * 512);
            async_copy16(Ag + (size_t)64 * 4096 + k0,     lds_a0 + (w + 4) * 512);
            async_copy16(Ag + k0 + 32,                    lds_a1 + w * 512);
            async_copy16(Ag + (size_t)64 * 4096 + k0 + 32, lds_a1 + (w + 4) * 512);
            async_copy16(Bg + k0,                         lds_b0 + w * 512);
            async_copy16(Bg + (size_t)64 * 4096 + k0,     lds_b0 + (w + 4) * 512);
            async_copy16(Bg + k0 + 32,                    lds_b1 + w * 512);
            async_copy16(Bg + (size_t)64 * 4096 + k0 + 32, lds_b1 + (w + 4) * 512);
            __syncthreads();
#pragma unroll
            for (int kk = 0; kk < 2; kk++) {
                const u16* la = kk ? lds_a1 : lds_a0;
                const u16* lb = kk ? lds_b1 : lds_b0;
                bf16x8 af[4], bfv[4];
#pragma unroll
                for (int i = 0; i < 4; i++)
                    af[i] = *(const bf16x8*)&la[(wm + i * 16 + l16) * 32 + quad * 8];
#pragma unroll
                for (int j = 0; j < 4; j++)
                    bfv[j] = *(const bf16x8*)&lb[(wn + j * 16 + l16) * 32 + quad * 8];
#pragma unroll
                for (int i = 0; i < 4; i++)
#pragma unroll
                    for (int j = 0; j < 4; j++)
                        acc[i][j] = __builtin_amdgcn_mfma_f32_16x16x32_bf16(af[i], bfv[j], acc[i][j], 0, 0, 0);
            }
            __syncthreads();
        }
        float* Vp = Vpart + (size_t)kslice * 2048 * 1024;
#pragma unroll
        for (int i = 0; i < 4; i++) {
            const int row = bm0 + wm + i * 16 + quad * 4;
#pragma unroll
            for (int j = 0; j < 4; j++) {
                const int col = bn0 + wn + j * 16 + l16;
#pragma unroll
                for (int r = 0; r < 4; r++)
                    Vp[(size_t)(row + r) * 1024 + col] = acc[i][j][r];
            }
        }
    }
}

// ---------------- O-projection GEMM: 2-way split-K, BK=64, atomic fp32 accumulate ----------------
// grid (64,16): bn = (x&31)*128, kslice = x>>5. 1024 blocks -> 4 blocks/CU.
// d_out is zeroed by hipMemsetAsync; the two k-slices accumulate via HW fp32 atomics
// (2 commutative adds per address -> deterministic). Replaces Opart + reduce pass.

__global__ __launch_bounds__(256) void gemm_o_k(const u16* __restrict__ A,
                                                const u16* __restrict__ B,
                                                float* __restrict__ Out) {
    __shared__ u16 lds[16384];   // 32 KB: a0,a1,b0,b1 of 128x32
    u16* lds_a0 = lds;
    u16* lds_a1 = lds + 4096;
    u16* lds_b0 = lds + 8192;
    u16* lds_b1 = lds + 12288;
    const int tid = threadIdx.x;
    const int w = tid >> 6, lane = tid & 63;
    const int quad = lane >> 4, l16 = lane & 15;
    const int bm0 = blockIdx.y * 128;
    const int bn0 = (blockIdx.x & 31) * 128;
    const int kslice = blockIdx.x >> 5;
    const int kb = kslice * 2048;
    const int wm = (w >> 1) * 64, wn = (w & 1) * 64;
    const int r0 = w * 16 + (lane >> 2);
    const int c0 = (lane & 3) * 8;
    const u16* Ag = A + (size_t)(bm0 + r0) * 4096 + kb + c0;
    const u16* Bg = B + (size_t)(bn0 + r0) * 4096 + kb + c0;
    f32x4 acc[4][4] = {};
    for (int k0 = 0; k0 < 2048; k0 += 64) {
        async_copy16(Ag + k0,                          lds_a0 + w * 512);
        async_copy16(Ag + (size_t)64 * 4096 + k0,      lds_a0 + (w + 4) * 512);
        async_copy16(Ag + k0 + 32,                     lds_a1 + w * 512);
        async_copy16(Ag + (size_t)64 * 4096 + k0 + 32, lds_a1 + (w + 4) * 512);
        async_copy16(Bg + k0,                          lds_b0 + w * 512);
        async_copy16(Bg + (size_t)64 * 4096 + k0,      lds_b0 + (w + 4) * 512);
        async_copy16(Bg + k0 + 32,                     lds_b1 + w * 512);
        async_copy16(Bg + (size_t)64 * 4096 + k0 + 32, lds_b1 + (w + 4) * 512);
        __syncthreads();
#pragma unroll
        for (int kk = 0; kk < 2; kk++) {
            const u16* la = kk ? lds_a1 : lds_a0;
            const u16* lb = kk ? lds_b1 : lds_b0;
            bf16x8 af[4], bfv[4];
#pragma unroll
            for (int i = 0; i < 4; i++)
                af[i] = *(const bf16x8*)&la[(wm + i * 16 + l16) * 32 + quad * 8];
#pragma unroll
            for (int j = 0; j < 4; j++)
                bfv[j] = *(const bf16x8*)&lb[(wn + j * 16 + l16) * 32 + quad * 8];
#pragma unroll
            for (int i = 0; i < 4; i++)
#pragma unroll
                for (int j = 0; j < 4; j++)
                    acc[i][j] = __builtin_amdgcn_mfma_f32_16x16x32_bf16(af[i], bfv[j], acc[i][j], 0, 0, 0);
        }
        __syncthreads();
    }
#pragma unroll
    for (int i = 0; i < 4; i++) {
        const int row = bm0 + wm + i * 16 + quad * 4;
#pragma unroll
        for (int j = 0; j < 4; j++) {
            const int col = bn0 + wn + j * 16 + l16;
#pragma unroll
            for (int r = 0; r < 4; r++)
                unsafeAtomicAdd(&Out[(size_t)(row + r) * 4096 + col], acc[i][j][r]);
        }
    }
}

// ---------------- fused flash attention (GQA, causal, no-max softmax) ----------------

__global__ __launch_bounds__(256) void attn_k(const u16* __restrict__ Qb,
                                              const u16* __restrict__ Kb,
                                              const u16* __restrict__ Vt,
                                              u16* __restrict__ Ob,
                                              int qstride, int kstride) {
    __shared__ u16 ldsK[4 * 64 * 32];   // [kk][key][hd32]
    __shared__ u16 ldsV[2 * 128 * 32];  // [ks][d][kappa32]
    __shared__ u16 ldsP[4][32 * 72];    // per-wave [m 32][kappa 64 + pad 8]
    const int h = blockIdx.x;
    const int qt = (int)gridDim.y - 1 - (int)blockIdx.y;  // heavy tiles first
    const int kvh = h >> 2;
    const int tid = threadIdx.x;
    const int w = tid >> 6, lane = tid & 63;
    const int quad = lane >> 4, l16 = lane & 15;
    const int q0 = qt * 128;
    const int wrow = q0 + w * 32;

    bf16x8 qf[2][4];
#pragma unroll
    for (int mi = 0; mi < 2; mi++)
#pragma unroll
        for (int kk = 0; kk < 4; kk++)
            qf[mi][kk] = *(const bf16x8*)&Qb[(size_t)(wrow + mi * 16 + l16) * qstride +
                                             h * 128 + kk * 32 + quad * 8];

    const u16* kp[4]; const u16* vp[4];
    u16* ldk[4]; u16* ldv[4];
#pragma unroll
    for (int t = 0; t < 4; t++) {
        int wl = w + t * 4;
        int kk = wl >> 2, part = wl & 3;
        kp[t] = Kb + (size_t)(part * 16 + (lane >> 2)) * kstride + kvh * 128 + kk * 32 + (lane & 3) * 8;
        int ks2 = wl >> 3, p2 = wl & 7;
        vp[t] = Vt + (size_t)(kvh * 128 + p2 * 16 + (lane >> 2)) * 2048 + ks2 * 32 + (lane & 3) * 8;
        ldk[t] = ldsK + wl * 512;
        ldv[t] = ldsV + wl * 512;
    }

    f32x4 acc_o[2][8] = {};
    float lrow[2][4] = {};

    const int nk = 2 * (qt + 1);
    for (int kn = 0; kn < nk; kn++) {
        const int g0 = kn * 64;
#pragma unroll
        for (int t = 0; t < 4; t++) async_copy16(kp[t], ldk[t]);
#pragma unroll
        for (int t = 0; t < 4; t++) async_copy16(vp[t], ldv[t]);
#pragma unroll
        for (int t = 0; t < 4; t++) { kp[t] += (size_t)64 * kstride; vp[t] += 64; }
        __syncthreads();

        if (g0 <= wrow + 31) {
            f32x4 accs[2][4] = {};
#pragma unroll
            for (int kk = 0; kk < 4; kk++) {
                bf16x8 bfrag[4];
#pragma unroll
                for (int ni = 0; ni < 4; ni++)
                    bfrag[ni] = *(const bf16x8*)&ldsK[kk * 2048 + (ni * 16 + l16) * 32 + quad * 8];
#pragma unroll
                for (int mi = 0; mi < 2; mi++)
#pragma unroll
                    for (int ni = 0; ni < 4; ni++)
                        accs[mi][ni] = __builtin_amdgcn_mfma_f32_16x16x32_bf16(
                            qf[mi][kk], bfrag[ni], accs[mi][ni], 0, 0, 0);
            }
            const bool diag = (g0 + 63 > wrow);
            int kidx[4];
#pragma unroll
            for (int ni = 0; ni < 4; ni++) kidx[ni] = g0 + ni * 16 + l16;
#pragma unroll
            for (int mi = 0; mi < 2; mi++) {
#pragma unroll
                for (int r = 0; r < 4; r++) {
                    const int qrow = wrow + mi * 16 + quad * 4 + r;
                    float p[4];
#pragma unroll
                    for (int ni = 0; ni < 4; ni++) {
                        float s = accs[mi][ni][r];
                        if (diag && (kidx[ni] > qrow)) s = -1e30f;
                        p[ni] = __expf(s);
                    }
                    lrow[mi][r] += (p[0] + p[1]) + (p[2] + p[3]);
                    uint2 pk;
                    pk.x = pack_bf2(p[0], p[1]);
                    pk.y = pack_bf2(p[2], p[3]);
                    *(uint2*)&ldsP[w][(mi * 16 + quad * 4 + r) * 72 + l16 * 4] = pk;
                }
            }
#pragma unroll
            for (int ks = 0; ks < 2; ks++) {
                bf16x8 pa[2];
#pragma unroll
                for (int mi = 0; mi < 2; mi++)
                    pa[mi] = *(const bf16x8*)&ldsP[w][(mi * 16 + l16) * 72 + ks * 32 + quad * 8];
#pragma unroll
                for (int oj = 0; oj < 8; oj++) {
                    bf16x8 vb = *(const bf16x8*)&ldsV[ks * 4096 + (oj * 16 + l16) * 32 + quad * 8];
#pragma unroll
                    for (int mi = 0; mi < 2; mi++)
                        acc_o[mi][oj] = __builtin_amdgcn_mfma_f32_16x16x32_bf16(
                            pa[mi], vb, acc_o[mi][oj], 0, 0, 0);
                }
            }
        }
        __syncthreads();
    }
#pragma unroll
    for (int mi = 0; mi < 2; mi++)
#pragma unroll
        for (int r = 0; r < 4; r++) {
            float l = lrow[mi][r];
            l += __shfl_xor(l, 1);
            l += __shfl_xor(l, 2);
            l += __shfl_xor(l, 4);
            l += __shfl_xor(l, 8);
            const float inv = 1.0f / l;
            const int qrow = wrow + mi * 16 + quad * 4 + r;
#pragma unroll
            for (int oj = 0; oj < 8; oj++)
                Ob[(size_t)qrow * 4096 + h * 128 + oj * 16 + l16] =
                    f2bf(acc_o[mi][oj][r] * inv);
        }
}

// ---------------- launch ----------------

extern "C" void kernel_launch(void* const* d_in, const int* in_sizes, int n_in,
                              void* d_out, int out_size, void* d_ws, size_t ws_size,
                              hipStream_t stream) {
    (void)in_sizes; (void)n_in; (void)out_size; (void)ws_size;
    const float* hidden = (const float*)d_in[0];
    const float* Wq = (const float*)d_in[1];
    const float* Wk = (const float*)d_in[2];
    const float* Wv = (const float*)d_in[3];
    const float* Wo = (const float*)d_in[4];
    const float* cosv = (const float*)d_in[5];
    const float* sinv = (const float*)d_in[6];
    const int* qoc = (const int*)d_in[8];
    const int* qor = (const int*)d_in[9];
    const int* koc = (const int*)d_in[10];
    const int* kor = (const int*)d_in[11];
    const int* voc = (const int*)d_in[12];
    const int* vor = (const int*)d_in[13];
    const int* ooc = (const int*)d_in[14];
    const int* oor = (const int*)d_in[15];

    char* ws = (char*)d_ws;
    size_t off = 0;
    // persistent across the whole pipeline:
    int* invq = (int*)(ws + off); off += 16384;
    int* invk = (int*)(ws + off); off += 16384;
    int* invv = (int*)(ws + off); off += 16384;
    int* invo = (int*)(ws + off); off += 16384;
    u16* Wop   = (u16*)(ws + off); off += (size_t)4096 * 4096 * 2;   // 33.5 MB (live at O-proj)
    u16* Xb    = (u16*)(ws + off); off += (size_t)2048 * 4096 * 2;   // 16.8 MB (live as Attb)
    u8*  Wqkf8 = (u8*)(ws + off);  off += (size_t)5120 * 4096;       // 21.0 MB
    u16* Wvp   = (u16*)(ws + off); off += (size_t)1024 * 4096 * 2;   //  8.4 MB
    u8*  Xf8   = (u8*)(ws + off);  off += (size_t)2048 * 4096;       //  8.4 MB
    u16* QKVb  = (u16*)(ws + off); off += (size_t)2048 * 6144 * 2;   // 25.2 MB
    u16* Vtb   = (u16*)(ws + off); off += (size_t)1024 * 2048 * 2;   //  4.2 MB
    float* Vpart = (float*)(ws + off); off += (size_t)2 * 2048 * 1024 * 4;  // 16.8 MB
    u16* Attb  = Xb;   // Xb dead after gemm_qkv_k; reuse for attention output

    inv4_k<<<64, 256, 0, stream>>>(qoc, koc, voc, ooc, invq, invk, invv, invo);
    permw4_k<<<10240, 256, 0, stream>>>(Wq, Wk, Wv, Wo, qor, kor, vor, oor,
                                        invq, invk, invv, invo, Wqkf8, Wvp, Wop);
    cvt_k<<<2048, 256, 0, stream>>>(hidden, Xb, Xf8);

    // QKV: Q,K via MX-fp8 (+fused RoPE/scale) + V via bf16 split-K2 -> QKVb + Vpart
    gemm_qkv_k<<<dim3(56, 16), 256, 0, stream>>>(Xf8, Xb, Wqkf8, Wvp, QKVb, Vpart,
                                                 cosv, sinv);

    // Vt build (sums split-K partials, kappa permutation)
    vtr_k<<<512, 256, 0, stream>>>(Vpart, Vtb);

    // attention -> Attb [2048][4096]  (reuses Xb storage)
    attn_k<<<dim3(32, 16), 256, 0, stream>>>(QKVb, QKVb + 4096, Vtb, Attb, 6144, 6144);

    // O-projection: split-K2 bf16, atomic fp32 accumulate into zeroed d_out
    hipMemsetAsync(d_out, 0, (size_t)2048 * 4096 * sizeof(float), stream);
    gemm_o_k<<<dim3(64, 16), 256, 0, stream>>>(Attb, Wop, (float*)d_out);
}

// Round 2
// 485.335 us; speedup vs baseline: 1.0891x; 1.0891x over previous
//
#include <hip/hip_runtime.h>

typedef unsigned short u16;
typedef unsigned char u8;
typedef __bf16 bf16x8 __attribute__((ext_vector_type(8)));
typedef float f32x4 __attribute__((ext_vector_type(4)));
typedef int i32x4 __attribute__((ext_vector_type(4)));
typedef int i32x8 __attribute__((ext_vector_type(8)));

__device__ __forceinline__ u16 f2bf(float f) {
    unsigned u = __float_as_uint(f);
    unsigned r = (u + 0x7fffu + ((u >> 16) & 1u)) >> 16;
    return (u16)r;
}
__device__ __forceinline__ float bf2f(u16 h) {
    return __uint_as_float(((unsigned)h) << 16);
}
// pack two floats to bf16x2 (lo in low half), round-half-up, single v_perm
__device__ __forceinline__ unsigned pack_bf2(float lo, float hi) {
    unsigned a = __float_as_uint(hi) + 0x8000u;
    unsigned b = __float_as_uint(lo) + 0x8000u;
    return __builtin_amdgcn_perm(a, b, 0x07060302u);
}
// pack 4 floats to 4 fp8 e4m3 bytes
__device__ __forceinline__ unsigned pack_fp8x4(float a, float b, float c, float d) {
    unsigned w = __builtin_amdgcn_cvt_pk_fp8_f32(a, b, 0, false);
    w = __builtin_amdgcn_cvt_pk_fp8_f32(c, d, w, true);
    return w;
}
__device__ __forceinline__ void async_copy16(const void* g, void* l) {
    __builtin_amdgcn_global_load_lds((__attribute__((address_space(1))) void*)(void*)g,
                                     (__attribute__((address_space(3))) void*)l, 16, 0, 0);
}

#define FP8_SCALE 64.0f          // pre-scale before e4m3 quant (avoids subnormals)
#define FP8_UNSCALE (1.0f / 4096.0f)  // (1/64)^2 applied at GEMM epilogue

// ---------------- prep kernels ----------------

__global__ void inv4_k(const int* __restrict__ q, const int* __restrict__ k,
                       const int* __restrict__ v, const int* __restrict__ o,
                       int* __restrict__ invq, int* __restrict__ invk,
                       int* __restrict__ invv, int* __restrict__ invo) {
    int i = blockIdx.x * 256 + threadIdx.x;   // grid 64 -> 16384 = 4*4096
    int a = i >> 12, j = i & 4095;
    const int* p = a == 0 ? q : a == 1 ? k : a == 2 ? v : o;
    int* inv = a == 0 ? invq : a == 1 ? invk : a == 2 ? invv : invo;
    inv[p[j]] = j;
}

// Weight permutations. Q,K rows -> fp8 (x64, XOR-swizzled 16B blocks); V,O rows -> bf16.
// Q,K additionally get a head-dim COLUMN permutation P (applied by selecting permuted
// weight rows) so RoPE pairs (d, d+64) land in adjacent j-fragments of one lane in the
// MFMA C-layout.  QK^T is invariant: Q and K share the same P.
//   P[hd] = (hd&15) | ((b&1)<<6) | ((b&2)<<3) | ((hd&64)>>1),  b = hd>>4
__global__ __launch_bounds__(256) void permw4_k(
    const float* __restrict__ Wq, const float* __restrict__ Wk,
    const float* __restrict__ Wv, const float* __restrict__ Wo,
    const int* __restrict__ qor, const int* __restrict__ kor,
    const int* __restrict__ vor, const int* __restrict__ oor,
    const int* __restrict__ invq, const int* __restrict__ invk,
    const int* __restrict__ invv, const int* __restrict__ invo,
    u8* __restrict__ Wqkf8, u16* __restrict__ Wvp, u16* __restrict__ Wop) {
    __shared__ float rowbuf[4096];
    int j = blockIdx.x;
    const float* W; const int* rp; const int* inv; int row; int f8;
    u8* out8 = nullptr; u16* out16 = nullptr;
    if (j < 4096)      { W = Wq; rp = qor; inv = invq; row = j;        out8 = Wqkf8 + (size_t)j * 4096; f8 = 1; }
    else if (j < 5120) { W = Wk; rp = kor; inv = invk; row = j - 4096; out8 = Wqkf8 + (size_t)j * 4096; f8 = 1; }
    else if (j < 6144) { W = Wv; rp = vor; inv = invv; row = j - 5120; out16 = Wvp + (size_t)(j - 5120) * 4096; f8 = 0; }
    else               { W = Wo; rp = oor; inv = invo; row = j - 6144; out16 = Wop + (size_t)(j - 6144) * 4096; f8 = 0; }
    if (f8) {   // head-dim column permutation for Q,K (RoPE pairing)
        int hd = row & 127, b = hd >> 4;
        row = (row & ~127) | ((hd & 15) | ((b & 1) << 6) | ((b & 2) << 3) | ((hd & 64) >> 1));
    }
    const float4* wr4 = (const float4*)(W + (size_t)rp[row] * 4096);
#pragma unroll
    for (int t = 0; t < 4; t++)
        ((float4*)rowbuf)[threadIdx.x + t * 256] = wr4[threadIdx.x + t * 256];
    __syncthreads();
    if (f8) {
        int t = threadIdx.x;                       // one 16B block per thread
        const int4* inv4p = (const int4*)inv;
        float v[16];
#pragma unroll
        for (int u = 0; u < 4; u++) {
            int4 ix = inv4p[t * 4 + u];
            v[4 * u + 0] = rowbuf[ix.x] * FP8_SCALE;
            v[4 * u + 1] = rowbuf[ix.y] * FP8_SCALE;
            v[4 * u + 2] = rowbuf[ix.z] * FP8_SCALE;
            v[4 * u + 3] = rowbuf[ix.w] * FP8_SCALE;
        }
        uint4 wv;
        wv.x = pack_fp8x4(v[0], v[1], v[2], v[3]);
        wv.y = pack_fp8x4(v[4], v[5], v[6], v[7]);
        wv.z = pack_fp8x4(v[8], v[9], v[10], v[11]);
        wv.w = pack_fp8x4(v[12], v[13], v[14], v[15]);
        int tb = (t & ~7) | ((t & 7) ^ (j & 7));   // XOR swizzle within 128B segment
        ((uint4*)out8)[tb] = wv;
    } else {
        unsigned* o32 = (unsigned*)out16;
        const int2* inv2 = (const int2*)inv;
#pragma unroll
        for (int t = 0; t < 8; t++) {
            int c = threadIdx.x + t * 256;
            int2 ij = inv2[c];
            o32[c] = pack_bf2(rowbuf[ij.x], rowbuf[ij.y]);
        }
    }
}

// hidden -> Xb (bf16) + Xf8 (fp8 x64, swizzled). One block per row of 4096.
__global__ __launch_bounds__(256) void cvt_k(const float* __restrict__ x,
                                             u16* __restrict__ Xb,
                                             u8* __restrict__ Xf8) {
    int row = blockIdx.x;
    int t = threadIdx.x;                           // 16 consecutive floats per thread
    const float4* src = (const float4*)(x + (size_t)row * 4096);
    float v[16];
#pragma unroll
    for (int u = 0; u < 4; u++) {
        float4 a = src[t * 4 + u];
        v[4 * u + 0] = a.x; v[4 * u + 1] = a.y; v[4 * u + 2] = a.z; v[4 * u + 3] = a.w;
    }
    uint4 b0, b1;
    b0.x = pack_bf2(v[0], v[1]);  b0.y = pack_bf2(v[2], v[3]);
    b0.z = pack_bf2(v[4], v[5]);  b0.w = pack_bf2(v[6], v[7]);
    b1.x = pack_bf2(v[8], v[9]);  b1.y = pack_bf2(v[10], v[11]);
    b1.z = pack_bf2(v[12], v[13]); b1.w = pack_bf2(v[14], v[15]);
    uint4* ob = (uint4*)(Xb + (size_t)row * 4096);
    ob[t * 2] = b0;
    ob[t * 2 + 1] = b1;
    uint4 w8;
    w8.x = pack_fp8x4(v[0] * FP8_SCALE, v[1] * FP8_SCALE, v[2] * FP8_SCALE, v[3] * FP8_SCALE);
    w8.y = pack_fp8x4(v[4] * FP8_SCALE, v[5] * FP8_SCALE, v[6] * FP8_SCALE, v[7] * FP8_SCALE);
    w8.z = pack_fp8x4(v[8] * FP8_SCALE, v[9] * FP8_SCALE, v[10] * FP8_SCALE, v[11] * FP8_SCALE);
    w8.w = pack_fp8x4(v[12] * FP8_SCALE, v[13] * FP8_SCALE, v[14] * FP8_SCALE, v[15] * FP8_SCALE);
    int tb = (t & ~7) | ((t & 7) ^ (row & 7));
    ((uint4*)(Xf8 + (size_t)row * 4096))[tb] = w8;
}

// V transpose (sums split-K fp32 partials, kappa-permuted cols). 512 blocks: 32 x 16.
__global__ __launch_bounds__(256) void vtr_k(const float* __restrict__ Vpart,
                                             u16* __restrict__ Vt) {
    __shared__ u16 t[64][65];
    int bx = blockIdx.x;
    int s0 = (bx & 31) * 64, c0 = (bx >> 5) * 64;
    int x = threadIdx.x & 63, y4 = threadIdx.x >> 6;
    const float* Vp0 = Vpart;
    const float* Vp1 = Vpart + (size_t)2048 * 1024;
    for (int i = 0; i < 16; i++) {
        int r = y4 * 16 + i;
        size_t idx = (size_t)(s0 + r) * 1024 + c0 + x;
        t[r][x] = f2bf(Vp0[idx] + Vp1[idx]);
    }
    __syncthreads();
    for (int i = 0; i < 16; i++) {
        int r = y4 * 16 + i;
        int xk = 4 * (x & 15) + (x >> 4);  // kappa permutation within 64-key tile
        Vt[(size_t)(c0 + r) * 2048 + s0 + xk] = t[x][r];
    }
}

// ---------------- merged QKV GEMM (balanced) ----------------
// blocks x<40: Q,K via MX-fp8 (128x128 tile, BK=128, 32 iters) + fused RoPE epilogue
// blocks x in [40,56): V via bf16, 2-way split-K, BK=64 -> 32 iters, fp32 partials.

__global__ __launch_bounds__(256) void gemm_qkv_k(const u8* __restrict__ Xf8,
                                                  const u16* __restrict__ Xb,
                                                  const u8* __restrict__ Wqk,
                                                  const u16* __restrict__ Wv,
                                                  u16* __restrict__ QKV,
                                                  float* __restrict__ Vpart,
                                                  const float* __restrict__ cosv,
                                                  const float* __restrict__ sinv) {
    __shared__ u8 lds[32768];
    const int tid = threadIdx.x;
    const int w = tid >> 6, lane = tid & 63;
    const int quad = lane >> 4, l16 = lane & 15;
    const int bm0 = blockIdx.y * 128;
    const int wm = (w >> 1) * 64, wn = (w & 1) * 64;
    if (blockIdx.x < 40) {
        const int bn0 = blockIdx.x * 128;
        u8* ldsA = lds;
        u8* ldsB = lds + 16384;
        const u8* Ag = Xf8 + (size_t)(bm0 + w * 32 + (lane >> 3)) * 4096 + (lane & 7) * 16;
        const u8* Bg = Wqk + (size_t)(bn0 + w * 32 + (lane >> 3)) * 4096 + (lane & 7) * 16;
        u8* la = ldsA + w * 32 * 128;
        u8* lb = ldsB + w * 32 * 128;
        const int swz = l16 & 7;   // (fragment row)&7 for XOR de-swizzle
        f32x4 acc[4][4] = {};
        for (int k0 = 0; k0 < 4096; k0 += 128) {
#pragma unroll
            for (int t = 0; t < 4; t++) async_copy16(Ag + (size_t)t * 8 * 4096 + k0, la + t * 1024);
#pragma unroll
            for (int t = 0; t < 4; t++) async_copy16(Bg + (size_t)t * 8 * 4096 + k0, lb + t * 1024);
            __syncthreads();
            i32x8 af[4], bf[4];
#pragma unroll
            for (int i = 0; i < 4; i++) {
                int r = wm + i * 16 + l16;
                union { i32x8 v8; i32x4 v4[2]; } u;
                u.v4[0] = *(const i32x4*)&ldsA[r * 128 + ((quad * 2) ^ swz) * 16];
                u.v4[1] = *(const i32x4*)&ldsA[r * 128 + ((quad * 2 + 1) ^ swz) * 16];
                af[i] = u.v8;
            }
#pragma unroll
            for (int j = 0; j < 4; j++) {
                int r = wn + j * 16 + l16;
                union { i32x8 v8; i32x4 v4[2]; } u;
                u.v4[0] = *(const i32x4*)&ldsB[r * 128 + ((quad * 2) ^ swz) * 16];
                u.v4[1] = *(const i32x4*)&ldsB[r * 128 + ((quad * 2 + 1) ^ swz) * 16];
                bf[j] = u.v8;
            }
#pragma unroll
            for (int i = 0; i < 4; i++)
#pragma unroll
                for (int j = 0; j < 4; j++)
                    acc[i][j] = __builtin_amdgcn_mfma_scale_f32_16x16x128_f8f6f4(
                        af[i], bf[j], acc[i][j], 0, 0,
                        0, 0x7F7F7F7F, 0, 0x7F7F7F7F);
            __syncthreads();
        }
        // fused RoPE epilogue: with the P column permutation, lane's cols hold
        //   j even -> head-dim d1, j odd -> head-dim d1+64 (same lane, same rows).
        //   cos[s,d1+64]==cos[s,d1], sin likewise.
        const float qsc = (bn0 < 4096) ? 0.08838834764831845f : 1.0f;  // 1/sqrt(128) for Q
        const int hb = (wn ? 32 : 0) + l16;
#pragma unroll
        for (int i = 0; i < 4; i++) {
            const int row = bm0 + wm + i * 16 + quad * 4;
#pragma unroll
            for (int jp = 0; jp < 2; jp++) {       // pair groups (j=0,1) and (j=2,3)
                const int d1 = hb + jp * 16;
                const int ce = bn0 + wn + jp * 32 + l16;
#pragma unroll
                for (int r = 0; r < 4; r++) {
                    const int s = row + r;
                    const float c  = cosv[s * 128 + d1];
                    const float sn = sinv[s * 128 + d1];
                    const float x1 = acc[i][jp * 2][r]     * FP8_UNSCALE;
                    const float x2 = acc[i][jp * 2 + 1][r] * FP8_UNSCALE;
                    QKV[(size_t)s * 6144 + ce]      = f2bf((x1 * c - x2 * sn) * qsc);
                    QKV[(size_t)s * 6144 + ce + 16] = f2bf((x2 * c + x1 * sn) * qsc);
                }
            }
        }
    } else {
        const int vx = blockIdx.x - 40;        // 16 slots: 8 n-tiles x 2 k-slices
        const int bn0 = (vx & 7) * 128;
        const int kslice = vx >> 3;
        const int kb = kslice * 2048;
        u16* lds_a0 = (u16*)lds;               // [128*32] each
        u16* lds_a1 = (u16*)(lds + 8192);
        u16* lds_b0 = (u16*)(lds + 16384);
        u16* lds_b1 = (u16*)(lds + 24576);
        const int r0 = w * 16 + (lane >> 2);
        const int c0 = (lane & 3) * 8;
        const u16* Ag = Xb + (size_t)(bm0 + r0) * 4096 + kb + c0;
        const u16* Bg = Wv + (size_t)(bn0 + r0) * 4096 + kb + c0;
        f32x4 acc[4][4] = {};
        for (int k0 = 0; k0 < 2048; k0 += 64) {
            async_copy16(Ag + k0,                         lds_a0 + w * 512);
            async_copy16(Ag + (size_t)64 * 4096 + k0,     lds_a0 + (w + 4) * 512);
            async_copy16(Ag + k0 + 32,                    lds_a1 + w * 512);
            async_copy16(Ag + (size_t)64 * 4096 + k0 + 32, lds_a1 + (w + 4) * 512);
            async_copy16(Bg + k0,                         lds_b0 + w * 512);
            async_copy16(Bg + (size_t)64 * 4096 + k0,     lds_b0 + (w + 4) * 512);
            async_copy16(Bg + k0 + 32,                    lds_b1 + w * 512);
            async_copy16(Bg + (size_t)64 * 4096 + k0 + 32, lds_b1 + (w + 4) * 512);
            __syncthreads();
#pragma unroll
            for (int kk = 0; kk < 2; kk++) {
                const u16* la = kk ? lds_a1 : lds_a0;
                const u16* lb = kk ? lds_b1 : lds_b0;
                bf16x8 af[4], bfv[4];
#pragma unroll
                for (int i = 0; i < 4; i++)
                    af[i] = *(const bf16x8*)&la[(wm + i * 16 + l16) * 32 + quad * 8];
#pragma unroll
                for (int j = 0; j < 4; j++)
                    bfv[j] = *(const bf16x8*)&lb[(wn + j * 16 + l16) * 32 + quad * 8];
#pragma unroll
                for (int i = 0; i < 4; i++)
#pragma unroll
                    for (int j = 0; j < 4; j++)
                        acc[i][j] = __builtin_amdgcn_mfma_f32_16x16x32_bf16(af[i], bfv[j], acc[i][j], 0, 0, 0);
            }
            __syncthreads();
        }
        float* Vp = Vpart + (size_t)kslice * 2048 * 1024;
#pragma unroll
        for (int i = 0; i < 4; i++) {
            const int row = bm0 + wm + i * 16 + quad * 4;
#pragma unroll
            for (int j = 0; j < 4; j++) {
                const int col = bn0 + wn + j * 16 + l16;
#pragma unroll
                for (int r = 0; r < 4; r++)
                    Vp[(size_t)(row + r) * 1024 + col] = acc[i][j][r];
            }
        }
    }
}

// ---------------- O-projection GEMM: single-pass K=4096, depth-3 counted-vmcnt pipeline --------
// BM=256, BN=128, BK=64. 512 thr (8 waves, 4Mx2N, 64x64/wave). LDS: 3 x 48KB buffers (dynamic).
// Stage uses inverse-swizzled global source (linear LDS dest); ds_read applies slot^=(row&7)
// -> conflict-free b128 batches. vmcnt(12) steady state (2 tiles in flight), peel 12->6->0.
// Direct fp32 store to d_out: no split-K, no atomics, no memset, no reduce.

#define GO_STAGE(bufi, kt) do {                                                   \
    u16* la_ = S + (bufi) * 24576;                                                \
    u16* lb_ = la_ + 16384;                                                       \
    const int k0_ = (kt) * 64;                                                    \
    _Pragma("unroll")                                                             \
    for (int u = 0; u < 4; u++)                                                   \
        async_copy16(Asrc + (size_t)u * 64 * 4096 + k0_, la_ + u * 4096 + sdst);  \
    _Pragma("unroll")                                                             \
    for (int u = 0; u < 2; u++)                                                   \
        async_copy16(Bsrc + (size_t)u * 64 * 4096 + k0_, lb_ + u * 4096 + sdst);  \
} while (0)

#define GO_COMPUTE(bufi) do {                                                     \
    const u16* la_ = S + (bufi) * 24576;                                          \
    const u16* lb_ = la_ + 16384;                                                 \
    bf16x8 bfr[4][2], afr[2][2];                                                  \
    _Pragma("unroll")                                                             \
    for (int j = 0; j < 4; j++) {                                                 \
        const int rb_ = (wn + j * 16 + l16) * 64;                                 \
        bfr[j][0] = *(const bf16x8*)&lb_[rb_ + o0];                               \
        bfr[j][1] = *(const bf16x8*)&lb_[rb_ + o1];                               \
    }                                                                             \
    _Pragma("unroll")                                                             \
    for (int i = 0; i < 2; i++) {                                                 \
        const int ra_ = (wm + i * 16 + l16) * 64;                                 \
        afr[i][0] = *(const bf16x8*)&la_[ra_ + o0];                               \
        afr[i][1] = *(const bf16x8*)&la_[ra_ + o1];                               \
    }                                                                             \
    asm volatile("s_waitcnt lgkmcnt(0)" ::: "memory");                            \
    __builtin_amdgcn_sched_barrier(0);                                            \
    __builtin_amdgcn_s_setprio(1);                                                \
    _Pragma("unroll")                                                             \
    for (int i = 0; i < 2; i++)                                                   \
        _Pragma("unroll")                                                         \
        for (int j = 0; j < 4; j++) {                                             \
            acc[i][j] = __builtin_amdgcn_mfma_f32_16x16x32_bf16(afr[i][0], bfr[j][0], acc[i][j], 0, 0, 0); \
            acc[i][j] = __builtin_amdgcn_mfma_f32_16x16x32_bf16(afr[i][1], bfr[j][1], acc[i][j], 0, 0, 0); \
        }                                                                         \
    __builtin_amdgcn_s_setprio(0);                                                \
    _Pragma("unroll")                                                             \
    for (int i = 0; i < 2; i++) {                                                 \
        const int ra_ = (wm + (i + 2) * 16 + l16) * 64;                           \
        afr[i][0] = *(const bf16x8*)&la_[ra_ + o0];                               \
        afr[i][1] = *(const bf16x8*)&la_[ra_ + o1];                               \
    }                                                                             \
    asm volatile("s_waitcnt lgkmcnt(0)" ::: "memory");                            \
    __builtin_amdgcn_sched_barrier(0);                                            \
    __builtin_amdgcn_s_setprio(1);                                                \
    _Pragma("unroll")                                                             \
    for (int i = 0; i < 2; i++)                                                   \
        _Pragma("unroll")                                                         \
        for (int j = 0; j < 4; j++) {                                             \
            acc[i + 2][j] = __builtin_amdgcn_mfma_f32_16x16x32_bf16(afr[i][0], bfr[j][0], acc[i + 2][j], 0, 0, 0); \
            acc[i + 2][j] = __builtin_amdgcn_mfma_f32_16x16x32_bf16(afr[i][1], bfr[j][1], acc[i + 2][j], 0, 0, 0); \
        }                                                                         \
    __builtin_amdgcn_s_setprio(0);                                                \
} while (0)

#define GO_BAR() asm volatile("s_barrier" ::: "memory")

__global__ __launch_bounds__(512, 2) void gemm_o_k(const u16* __restrict__ A,
                                                   const u16* __restrict__ B,
                                                   float* __restrict__ Out) {
    extern __shared__ u16 S[];                 // 3 * 49152 B = 144 KB
    const int tid = threadIdx.x;
    const int w = tid >> 6, lane = tid & 63;
    const int quad = lane >> 4, l16 = lane & 15;
    // XCD-bijective swizzle over 256 blocks: each XCD gets one contiguous m-row (A-panel L2-resident)
    const int linear = blockIdx.y * 32 + blockIdx.x;
    const int wgid = (linear & 7) * 32 + (linear >> 3);
    const int bm0 = (wgid >> 5) * 256;
    const int bn0 = (wgid & 31) * 128;
    const int wm = (w >> 1) * 64;              // 4 waves along M
    const int wn = (w & 1) * 64;               // 2 waves along N
    // staging: thread -> (row = u*64 + tid>>3, col16B = (tid&7) ^ (row&7))  [inverse swizzle]
    const int sr = tid >> 3;
    const int scg = ((tid & 7) ^ (sr & 7)) * 8;
    const int sdst = tid * 8;                  // u16 units (16B/thread)
    const u16* Asrc = A + (size_t)(bm0 + sr) * 4096 + scg;
    const u16* Bsrc = B + (size_t)(bn0 + sr) * 4096 + scg;
    // fragment read swizzle: slot = ((kk<<2)|quad) ^ (row&7); row&7 == l16&7 here
    const int swz = l16 & 7;
    const int o0 = (quad ^ swz) * 8;           // u16 offset for kk=0
    const int o1 = ((4 | quad) ^ swz) * 8;     // u16 offset for kk=1

    f32x4 acc[4][4] = {};

    GO_STAGE(0, 0);
    GO_STAGE(1, 1);
    GO_STAGE(2, 2);
    asm volatile("s_waitcnt vmcnt(12)" ::: "memory");   // tile 0 landed
    GO_BAR();

    int cur = 0;
    for (int t = 0; t < 61; ++t) {
        GO_COMPUTE(cur);
        GO_BAR();                                        // all waves done reading buf[cur]
        GO_STAGE(cur, t + 3);
        asm volatile("s_waitcnt vmcnt(12)" ::: "memory"); // tile t+1 landed (t+2,t+3 in flight)
        GO_BAR();
        cur = (cur == 2) ? 0 : cur + 1;
    }
    // t = 61 (buf 1): tile 63's 6 loads may still be in flight
    GO_COMPUTE(1);
    asm volatile("s_waitcnt vmcnt(6)" ::: "memory");      // tile 62 landed
    GO_BAR();
    // t = 62 (buf 2)
    GO_COMPUTE(2);
    asm volatile("s_waitcnt vmcnt(0)" ::: "memory");      // tile 63 landed
    GO_BAR();
    // t = 63 (buf 0)
    GO_COMPUTE(0);

#pragma unroll
    for (int i = 0; i < 4; i++) {
        const int row = bm0 + wm + i * 16 + quad * 4;
#pragma unroll
        for (int j = 0; j < 4; j++) {
            const int col = bn0 + wn + j * 16 + l16;
#pragma unroll
            for (int r = 0; r < 4; r++)
                Out[(size_t)(row + r) * 4096 + col] = acc[i][j][r];
        }
    }
}

// ---------------- fused flash attention (GQA, causal, no-max softmax) ----------------

__global__ __launch_bounds__(256) void attn_k(const u16* __restrict__ Qb,
                                              const u16* __restrict__ Kb,
                                              const u16* __restrict__ Vt,
                                              u16* __restrict__ Ob,
                                              int qstride, int kstride) {
    __shared__ u16 ldsK[4 * 64 * 32];   // [kk][key][hd32]
    __shared__ u16 ldsV[2 * 128 * 32];  // [ks][d][kappa32]
    __shared__ u16 ldsP[4][32 * 72];    // per-wave [m 32][kappa 64 + pad 8]
    const int h = blockIdx.x;
    const int qt = (int)gridDim.y - 1 - (int)blockIdx.y;  // heavy tiles first
    const int kvh = h >> 2;
    const int tid = threadIdx.x;
    const int w = tid >> 6, lane = tid & 63;
    const int quad = lane >> 4, l16 = lane & 15;
    const int q0 = qt * 128;
    const int wrow = q0 + w * 32;

    bf16x8 qf[2][4];
#pragma unroll
    for (int mi = 0; mi < 2; mi++)
#pragma unroll
        for (int kk = 0; kk < 4; kk++)
            qf[mi][kk] = *(const bf16x8*)&Qb[(size_t)(wrow + mi * 16 + l16) * qstride +
                                             h * 128 + kk * 32 + quad * 8];

    const u16* kp[4]; const u16* vp[4];
    u16* ldk[4]; u16* ldv[4];
#pragma unroll
    for (int t = 0; t < 4; t++) {
        int wl = w + t * 4;
        int kk = wl >> 2, part = wl & 3;
        kp[t] = Kb + (size_t)(part * 16 + (lane >> 2)) * kstride + kvh * 128 + kk * 32 + (lane & 3) * 8;
        int ks2 = wl >> 3, p2 = wl & 7;
        vp[t] = Vt + (size_t)(kvh * 128 + p2 * 16 + (lane >> 2)) * 2048 + ks2 * 32 + (lane & 3) * 8;
        ldk[t] = ldsK + wl * 512;
        ldv[t] = ldsV + wl * 512;
    }

    f32x4 acc_o[2][8] = {};
    float lrow[2][4] = {};

    const int nk = 2 * (qt + 1);
    for (int kn = 0; kn < nk; kn++) {
        const int g0 = kn * 64;
#pragma unroll
        for (int t = 0; t < 4; t++) async_copy16(kp[t], ldk[t]);
#pragma unroll
        for (int t = 0; t < 4; t++) async_copy16(vp[t], ldv[t]);
#pragma unroll
        for (int t = 0; t < 4; t++) { kp[t] += (size_t)64 * kstride; vp[t] += 64; }
        __syncthreads();

        if (g0 <= wrow + 31) {
            f32x4 accs[2][4] = {};
#pragma unroll
            for (int kk = 0; kk < 4; kk++) {
                bf16x8 bfrag[4];
#pragma unroll
                for (int ni = 0; ni < 4; ni++)
                    bfrag[ni] = *(const bf16x8*)&ldsK[kk * 2048 + (ni * 16 + l16) * 32 + quad * 8];
#pragma unroll
                for (int mi = 0; mi < 2; mi++)
#pragma unroll
                    for (int ni = 0; ni < 4; ni++)
                        accs[mi][ni] = __builtin_amdgcn_mfma_f32_16x16x32_bf16(
                            qf[mi][kk], bfrag[ni], accs[mi][ni], 0, 0, 0);
            }
            const bool diag = (g0 + 63 > wrow);
            int kidx[4];
#pragma unroll
            for (int ni = 0; ni < 4; ni++) kidx[ni] = g0 + ni * 16 + l16;
#pragma unroll
            for (int mi = 0; mi < 2; mi++) {
#pragma unroll
                for (int r = 0; r < 4; r++) {
                    const int qrow = wrow + mi * 16 + quad * 4 + r;
                    float p[4];
#pragma unroll
                    for (int ni = 0; ni < 4; ni++) {
                        float s = accs[mi][ni][r];
                        if (diag && (kidx[ni] > qrow)) s = -1e30f;
                        p[ni] = __expf(s);
                    }
                    lrow[mi][r] += (p[0] + p[1]) + (p[2] + p[3]);
                    uint2 pk;
                    pk.x = pack_bf2(p[0], p[1]);
                    pk.y = pack_bf2(p[2], p[3]);
                    *(uint2*)&ldsP[w][(mi * 16 + quad * 4 + r) * 72 + l16 * 4] = pk;
                }
            }
#pragma unroll
            for (int ks = 0; ks < 2; ks++) {
                bf16x8 pa[2];
#pragma unroll
                for (int mi = 0; mi < 2; mi++)
                    pa[mi] = *(const bf16x8*)&ldsP[w][(mi * 16 + l16) * 72 + ks * 32 + quad * 8];
#pragma unroll
                for (int oj = 0; oj < 8; oj++) {
                    bf16x8 vb = *(const bf16x8*)&ldsV[ks * 4096 + (oj * 16 + l16) * 32 + quad * 8];
#pragma unroll
                    for (int mi = 0; mi < 2; mi++)
                        acc_o[mi][oj] = __builtin_amdgcn_mfma_f32_16x16x32_bf16(
                            pa[mi], vb, acc_o[mi][oj], 0, 0, 0);
                }
            }
        }
        __syncthreads();
    }
#pragma unroll
    for (int mi = 0; mi < 2; mi++)
#pragma unroll
        for (int r = 0; r < 4; r++) {
            float l = lrow[mi][r];
            l += __shfl_xor(l, 1);
            l += __shfl_xor(l, 2);
            l += __shfl_xor(l, 4);
            l += __shfl_xor(l, 8);
            const float inv = 1.0f / l;
            const int qrow = wrow + mi * 16 + quad * 4 + r;
#pragma unroll
            for (int oj = 0; oj < 8; oj++)
                Ob[(size_t)qrow * 4096 + h * 128 + oj * 16 + l16] =
                    f2bf(acc_o[mi][oj][r] * inv);
        }
}

// ---------------- launch ----------------

extern "C" void kernel_launch(void* const* d_in, const int* in_sizes, int n_in,
                              void* d_out, int out_size, void* d_ws, size_t ws_size,
                              hipStream_t stream) {
    (void)in_sizes; (void)n_in; (void)out_size; (void)ws_size;
    const float* hidden = (const float*)d_in[0];
    const float* Wq = (const float*)d_in[1];
    const float* Wk = (const float*)d_in[2];
    const float* Wv = (const float*)d_in[3];
    const float* Wo = (const float*)d_in[4];
    const float* cosv = (const float*)d_in[5];
    const float* sinv = (const float*)d_in[6];
    const int* qoc = (const int*)d_in[8];
    const int* qor = (const int*)d_in[9];
    const int* koc = (const int*)d_in[10];
    const int* kor = (const int*)d_in[11];
    const int* voc = (const int*)d_in[12];
    const int* vor = (const int*)d_in[13];
    const int* ooc = (const int*)d_in[14];
    const int* oor = (const int*)d_in[15];

    char* ws = (char*)d_ws;
    size_t off = 0;
    // persistent across the whole pipeline:
    int* invq = (int*)(ws + off); off += 16384;
    int* invk = (int*)(ws + off); off += 16384;
    int* invv = (int*)(ws + off); off += 16384;
    int* invo = (int*)(ws + off); off += 16384;
    u16* Wop   = (u16*)(ws + off); off += (size_t)4096 * 4096 * 2;   // 33.5 MB (live at O-proj)
    u16* Xb    = (u16*)(ws + off); off += (size_t)2048 * 4096 * 2;   // 16.8 MB (live as Attb)
    u8*  Wqkf8 = (u8*)(ws + off);  off += (size_t)5120 * 4096;       // 21.0 MB
    u16* Wvp   = (u16*)(ws + off); off += (size_t)1024 * 4096 * 2;   //  8.4 MB
    u8*  Xf8   = (u8*)(ws + off);  off += (size_t)2048 * 4096;       //  8.4 MB
    u16* QKVb  = (u16*)(ws + off); off += (size_t)2048 * 6144 * 2;   // 25.2 MB
    u16* Vtb   = (u16*)(ws + off); off += (size_t)1024 * 2048 * 2;   //  4.2 MB
    float* Vpart = (float*)(ws + off); off += (size_t)2 * 2048 * 1024 * 4;  // 16.8 MB
    u16* Attb  = Xb;   // Xb dead after gemm_qkv_k; reuse for attention output

    inv4_k<<<64, 256, 0, stream>>>(qoc, koc, voc, ooc, invq, invk, invv, invo);
    permw4_k<<<10240, 256, 0, stream>>>(Wq, Wk, Wv, Wo, qor, kor, vor, oor,
                                        invq, invk, invv, invo, Wqkf8, Wvp, Wop);
    cvt_k<<<2048, 256, 0, stream>>>(hidden, Xb, Xf8);

    // QKV: Q,K via MX-fp8 (+fused RoPE/scale) + V via bf16 split-K2 -> QKVb + Vpart
    gemm_qkv_k<<<dim3(56, 16), 256, 0, stream>>>(Xf8, Xb, Wqkf8, Wvp, QKVb, Vpart,
                                                 cosv, sinv);

    // Vt build (sums split-K partials, kappa permutation)
    vtr_k<<<512, 256, 0, stream>>>(Vpart, Vtb);

    // attention -> Attb [2048][4096]  (reuses Xb storage)
    attn_k<<<dim3(32, 16), 256, 0, stream>>>(QKVb, QKVb + 4096, Vtb, Attb, 6144, 6144);

    // O-projection: single-pass pipelined bf16 GEMM, direct fp32 store
    gemm_o_k<<<dim3(32, 8), 512, 147456, stream>>>(Attb, Wop, (float*)d_out);
}